// Round 5
// baseline (83.878 us; speedup 1.0000x reference)
//
#include <hip/hip_runtime.h>

// Degrade: per-sample depthwise 13x13 cross-correlation, stride 4,
// replicate padding p=6.  im: [8,4,1024,1024] f32, kernel: [8,1,13,13] f32,
// out: [8,4,256,256] f32.
//
// R4: kill the TA bottleneck (R0-R3 model: ~1 distinct-line touch/cyc/CU).
//  - LDS-stage the 73x140 input tile per 32x16 output block with fully
//    coalesced float4 staging (TA ~4us vs ~36us for per-thread gathers).
//  - chunk XOR swizzle (c ^ ((c>>3)&7), row stride padded to 40 chunks)
//    makes the lane-stride-64B ds_read_b128 pattern conflict-free
//    (enumerated: 4 phases perfect, 3 with a free 2-way alias).
//  - kernel weights read via wave-UNIFORM global address -> s_load (scalar
//    pipe), deleting the 208 ds_read_b128/thread weight traffic R0-R3 paid.
//  - clamping (replicate pad) handled once at stage time; compute loop is
//    branch-free.

#define KS 13
#define PAD 6
#define IH 1024
#define IW 1024
#define OH 256
#define OW 256

#define BW 32            // block output width
#define BH 16            // block output height
#define ROWS (BH * 4 + 9)   // 73 input rows per tile
#define CCH 35           // 16B chunks used per row (140 floats)
#define CST 40           // chunk row stride (padded to mult of 8 for swizzle)
#define NCH (ROWS * CCH) // 2555 chunks to stage
#define NTHR 128

__device__ __forceinline__ int swz(int c) { return c ^ ((c >> 3) & 7); }

__global__ __launch_bounds__(NTHR) void degrade_kernel(
    const float* __restrict__ im,
    const float* __restrict__ kern,
    float* __restrict__ out)
{
    __shared__ float tile[ROWS * CST * 4];   // 46720 B -> 3 blocks/CU

    const int plane = blockIdx.z;            // b*4 + c
    const int b     = plane >> 2;
    const int tid   = threadIdx.x;
    const int OX0   = blockIdx.x * BW;
    const int OY0   = blockIdx.y * BH;
    const int row0  = 4 * OY0 - PAD;
    const int col0  = 4 * OX0 - 8;           // 16B-aligned window start

    const float* __restrict__ pl = im + (size_t)plane * (IH * IW);

    // ---- stage input tile (replicate-clamped), coalesced float4 ----
    for (int l = tid; l < NCH; l += NTHR) {
        const int r  = l / CCH;              // compile-time magic-div
        const int cc = l - r * CCH;
        const int gy = min(max(row0 + r, 0), IH - 1);
        const int gc = col0 + 4 * cc;
        const float* __restrict__ grow = pl + (size_t)gy * IW;
        float4 val;
        if (gc >= 0 && gc + 3 < IW) {
            val = *(const float4*)(grow + gc);
        } else {                              // image border only
            val.x = grow[min(max(gc + 0, 0), IW - 1)];
            val.y = grow[min(max(gc + 1, 0), IW - 1)];
            val.z = grow[min(max(gc + 2, 0), IW - 1)];
            val.w = grow[min(max(gc + 3, 0), IW - 1)];
        }
        *(float4*)&tile[(r * CST + swz(cc)) * 4] = val;
    }
    __syncthreads();

    const int tx = tid & 7;                  // 8 threads x, 4 outputs each
    const int ty = tid >> 3;                 // 16 threads y, 1 output each

    // swizzled byte offsets (as float index) of this lane's 7 window chunks
    int coff[7];
#pragma unroll
    for (int q = 0; q < 7; ++q) coff[q] = swz(4 * tx + q) * 4;

    const float* __restrict__ kb = kern + b * (KS * KS);  // wave-uniform

    float acc0 = 0.f, acc1 = 0.f, acc2 = 0.f, acc3 = 0.f;

#pragma unroll 2
    for (int ky = 0; ky < KS; ++ky) {
        const int r = 4 * ty + ky;
        const float* __restrict__ trow = &tile[r * (CST * 4)];

        float v[28];                          // all indices compile-time
#pragma unroll
        for (int q = 0; q < 7; ++q) {
            float4 x = *(const float4*)(trow + coff[q]);
            v[4 * q + 0] = x.x; v[4 * q + 1] = x.y;
            v[4 * q + 2] = x.z; v[4 * q + 3] = x.w;
        }

        float kw[KS];                         // uniform addr -> s_load
#pragma unroll
        for (int kx = 0; kx < KS; ++kx) kw[kx] = kb[ky * KS + kx];

#pragma unroll
        for (int kx = 0; kx < KS; ++kx) {
            acc0 = fmaf(v[2  + kx], kw[kx], acc0);
            acc1 = fmaf(v[6  + kx], kw[kx], acc1);
            acc2 = fmaf(v[10 + kx], kw[kx], acc2);
            acc3 = fmaf(v[14 + kx], kw[kx], acc3);
        }
    }

    const int oy = OY0 + ty;
    *(float4*)(out + ((size_t)plane * OH + oy) * OW + OX0 + 4 * tx) =
        make_float4(acc0, acc1, acc2, acc3);
}

extern "C" void kernel_launch(void* const* d_in, const int* in_sizes, int n_in,
                              void* d_out, int out_size, void* d_ws, size_t ws_size,
                              hipStream_t stream)
{
    const float* im   = (const float*)d_in[0];
    const float* kern = (const float*)d_in[1];
    float* out        = (float*)d_out;

    dim3 grid(OW / BW, OH / BH, 32);   // 8 x 16 x 32 = 4096 blocks
    degrade_kernel<<<grid, NTHR, 0, stream>>>(im, kern, out);
}

// Round 6
// 59.506 us; speedup vs baseline: 1.4096x; 1.4096x over previous
//
#include <hip/hip_runtime.h>

// Degrade: per-sample depthwise 13x13 cross-correlation, stride 4,
// replicate padding p=6.  im: [8,4,1024,1024] f32, kernel: [8,1,13,13] f32,
// out: [8,4,256,256] f32.
//
// R5: coalesced-gather structure from the (4/4-validated) TA line-touch
// model: time ~ distinct-line-touches / (1 per cyc per CU).
//   touches/output = loads_per_row * rows * min(1,TW/4) / (TW*TH)
//   R3 (TW=4,TH=4): 10.9 -> 46us.   R5 (TW=1,TH=4): 4*25*0.25/4 = 6.25
//   -> ~21us ~= HBM floor (131 MB / 6.3 TB/s).
// TW=1: lane window base strides 16 B -> 4 lanes/line per float4 gather
// (vs 1 line/lane at TW=4).  TH=4 keeps vertical reuse in registers.
// No LDS at all: weights via wave-uniform address -> scalar s_load pipe
// (R4 confirmed scalarization; R4's LDS staging + its bank aliasing and
// occupancy cliff are reverted).  524K threads = 8192 waves.

#define KS 13
#define PAD 6
#define IH 1024
#define IW 1024
#define OH 256
#define OW 256
#define TH 4          // output rows per thread

__global__ __launch_bounds__(256) void degrade_kernel(
    const float* __restrict__ im,
    const float* __restrict__ kern,
    float* __restrict__ out)
{
    const int plane  = blockIdx.z;        // b*4 + c
    const int b      = plane >> 2;
    const int tid    = threadIdx.x;
    const int lane_x = tid & 63;          // 64 lanes across x, 1 output col each
    const int yg     = tid >> 6;          // 4 y-groups, TH rows each
    const int ox     = blockIdx.x * 64 + lane_x;
    const int oy0    = blockIdx.y * 16 + yg * TH;

    const float* __restrict__ pl = im + (size_t)plane * (IH * IW);
    const float* __restrict__ kb = kern + b * (KS * KS);   // wave-uniform

    // 16-float aligned window per row: base = 4*ox - 8 (taps at v[2..14])
    const int abase     = 4 * ox - 8;
    const bool interior = (abase >= 0) && (abase + 16 <= IW);
    const int gy0       = 4 * oy0 - PAD;

    float acc[TH];
#pragma unroll
    for (int j = 0; j < TH; ++j) acc[j] = 0.0f;

    // 4*TH+9 = 25 input rows feed this thread's TH output rows; runtime
    // loop (R2 lesson: full unroll -> 256 VGPR -> occupancy collapse).
#pragma unroll 1
    for (int t = 0; t < 4 * TH + 9; ++t) {
        const int gy = min(max(gy0 + t, 0), IH - 1);
        const float* __restrict__ row = pl + (size_t)gy * IW;

        float v[16];
        if (interior) {                   // coalesced: lane stride 16 B
            const float4* __restrict__ rp = (const float4*)(row + abase);
#pragma unroll
            for (int q = 0; q < 4; ++q) {
                float4 x = rp[q];
                v[4 * q + 0] = x.x; v[4 * q + 1] = x.y;
                v[4 * q + 2] = x.z; v[4 * q + 3] = x.w;
            }
        } else {                          // only lanes at image border
#pragma unroll
            for (int u = 0; u < 16; ++u)
                v[u] = row[min(max(abase + u, 0), IW - 1)];
        }

#pragma unroll
        for (int j = 0; j < TH; ++j) {
            const int ky = t - 4 * j;
            if (ky >= 0 && ky < KS) {     // wave-uniform branch
#pragma unroll
                for (int kx = 0; kx < KS; ++kx)
                    acc[j] = fmaf(v[2 + kx], kb[ky * KS + kx], acc[j]);
            }
        }
    }

#pragma unroll
    for (int j = 0; j < TH; ++j)
        out[((size_t)plane * OH + oy0 + j) * OW + ox] = acc[j];
}

extern "C" void kernel_launch(void* const* d_in, const int* in_sizes, int n_in,
                              void* d_out, int out_size, void* d_ws, size_t ws_size,
                              hipStream_t stream)
{
    const float* im   = (const float*)d_in[0];
    const float* kern = (const float*)d_in[1];
    float* out        = (float*)d_out;

    dim3 grid(OW / 64, OH / 16, 32);   // 4 x 16 x 32 = 2048 blocks
    degrade_kernel<<<grid, 256, 0, stream>>>(im, kern, out);
}

// Round 7
// 50.918 us; speedup vs baseline: 1.6473x; 1.1687x over previous
//
#include <hip/hip_runtime.h>

// Degrade: per-sample depthwise 13x13 cross-correlation, stride 4,
// replicate padding p=6.  im: [8,4,1024,1024] f32, kernel: [8,1,13,13] f32,
// out: [8,4,256,256] f32.
//
// R6: scatter-partial wave-cooperative conv.  Model (5/5 round fit): cost ~
// 1 VMEM lane-address per cycle per CU; R5 wasted 4x on horizontal chunk
// redundancy.  Here each lane loads ONE float4 chunk per input row (chunk
// lane, contiguous 1024B per wave-instr) and scatters it into 4 partial
// accumulators (for outputs m = lane-3..lane, tap kx = 4p+c-2, compile-time).
// Cross-lane combine ONCE at the end via 3 shfl per output row.  Wave covers
// 61 outputs so shfl wrap only feeds invalid lanes (no halo special case).
// TH=8 rows/thread (vertical re-read 41/32).  Ping-pong A/B row pipeline
// (static names).  Weights via wave-uniform address -> scalar pipe.
// Lane-addresses: 5120 waves x 41 x 64 = 13.4M -> ~22 us ~= HBM floor.

#define KS 13
#define IH 1024
#define IW 1024
#define OH 256
#define OW 256
#define WOX 61        // valid outputs per wave in x
#define TH 8          // output rows per thread
#define NROWS (4 * TH + 9)   // 41 input rows per thread

__global__ __launch_bounds__(256, 5) void degrade_kernel(
    const float* __restrict__ im,
    const float* __restrict__ kern,
    float* __restrict__ out)
{
    const int plane = blockIdx.z;          // b*4 + c
    const int b     = plane >> 2;
    const int tid   = threadIdx.x;
    const int lane  = tid & 63;
    const int w     = tid >> 6;            // wave in block
    const int ox0   = blockIdx.x * WOX;
    const int oy0   = blockIdx.y * (4 * TH) + w * TH;

    const float* __restrict__ pl = im + (size_t)plane * (IH * IW);
    const float* __restrict__ kb = kern + b * (KS * KS);   // wave-uniform

    // this lane's chunk: floats fbase..fbase+3 of each input row
    const int fbase  = 4 * ox0 - 8 + 4 * lane;
    const bool vec_ok = (fbase >= 0) && (fbase + 3 < IW);
    const int c0 = min(max(fbase + 0, 0), IW - 1);   // clamped offsets,
    const int c1 = min(max(fbase + 1, 0), IW - 1);   // row-independent
    const int c2 = min(max(fbase + 2, 0), IW - 1);
    const int c3 = min(max(fbase + 3, 0), IW - 1);

    const int gy0 = 4 * oy0 - 6;

    // acc[j][p]: partial for output (oy0+j, ox0+lane-p)
    float acc[TH][4];
#pragma unroll
    for (int j = 0; j < TH; ++j)
#pragma unroll
        for (int p = 0; p < 4; ++p) acc[j][p] = 0.0f;

    auto load_row = [&](int t) -> float4 {
        const int gy = min(max(gy0 + t, 0), IH - 1);
        const float* __restrict__ row = pl + (size_t)gy * IW;
        float4 x;
        if (vec_ok) {
            x = *(const float4*)(row + fbase);
        } else {                            // image x-border lanes only
            x.x = row[c0]; x.y = row[c1]; x.z = row[c2]; x.w = row[c3];
        }
        return x;
    };

    // chunk float c covers tap kx = 4p + c - 2 of output (lane - p)
    auto fma_row = [&](const float4& v, int t) {
#pragma unroll
        for (int j = 0; j < TH; ++j) {
            const int ky = t - 4 * j;       // runtime, wave-uniform
            if (ky >= 0 && ky < KS) {
                const float* __restrict__ kr = kb + ky * KS;  // s_load pipe
                acc[j][0] = fmaf(v.z, kr[0],  acc[j][0]);
                acc[j][0] = fmaf(v.w, kr[1],  acc[j][0]);
                acc[j][1] = fmaf(v.x, kr[2],  acc[j][1]);
                acc[j][1] = fmaf(v.y, kr[3],  acc[j][1]);
                acc[j][1] = fmaf(v.z, kr[4],  acc[j][1]);
                acc[j][1] = fmaf(v.w, kr[5],  acc[j][1]);
                acc[j][2] = fmaf(v.x, kr[6],  acc[j][2]);
                acc[j][2] = fmaf(v.y, kr[7],  acc[j][2]);
                acc[j][2] = fmaf(v.z, kr[8],  acc[j][2]);
                acc[j][2] = fmaf(v.w, kr[9],  acc[j][2]);
                acc[j][3] = fmaf(v.x, kr[10], acc[j][3]);
                acc[j][3] = fmaf(v.y, kr[11], acc[j][3]);
                acc[j][3] = fmaf(v.z, kr[12], acc[j][3]);
            }
        }
    };

    // ping-pong software pipeline over NROWS=41 input rows (exactly 41 loads)
    float4 A = load_row(0);
#pragma unroll 1
    for (int t = 0; t < NROWS - 2; t += 2) {   // t = 0,2,...,38
        float4 B = load_row(t + 1);
        fma_row(A, t);
        A = load_row(t + 2);
        fma_row(B, t + 1);
    }
    fma_row(A, NROWS - 1);                     // t = 40

    // combine partials across lanes (once) and store
    const bool valid = (lane < WOX) && (ox0 + lane < OW);
#pragma unroll
    for (int j = 0; j < TH; ++j) {
        float v = acc[j][0]
                + __shfl(acc[j][1], lane + 1, 64)
                + __shfl(acc[j][2], lane + 2, 64)
                + __shfl(acc[j][3], lane + 3, 64);
        if (valid)
            out[((size_t)plane * OH + oy0 + j) * OW + ox0 + lane] = v;
    }
}

extern "C" void kernel_launch(void* const* d_in, const int* in_sizes, int n_in,
                              void* d_out, int out_size, void* d_ws, size_t ws_size,
                              hipStream_t stream)
{
    const float* im   = (const float*)d_in[0];
    const float* kern = (const float*)d_in[1];
    float* out        = (float*)d_out;

    dim3 grid((OW + WOX - 1) / WOX,        // 5
              OH / (4 * TH),               // 8
              32);                         // 1280 blocks = 5120 waves
    degrade_kernel<<<grid, 256, 0, stream>>>(im, kern, out);
}

// Round 8
// 48.810 us; speedup vs baseline: 1.7185x; 1.0432x over previous
//
#include <hip/hip_runtime.h>

// Degrade: per-sample depthwise 13x13 cross-correlation, stride 4,
// replicate padding p=6.  im: [8,4,1024,1024] f32, kernel: [8,1,13,13] f32,
// out: [8,4,256,256] f32.
//
// R7: R6's cooperative structure (1 coalesced float4 chunk per lane per
// input row; 4 scatter-partials per output row; one 3-shfl combine at the
// end) with the execution defects fixed:
//  - ky-PHASE decomposition: rows with t%4==r share the compile-time ky set
//    {r,r+4,r+8,r+12}.  4 unrolled phases -> zero branches in the hot loop,
//    weight indices compile-time (uniform+invariant -> hoisted s_loads),
//    loads pipelined by the compiler across straight-line unrolled rows.
//  - no launch_bounds min-wave cap (R6 likely spilled under 96-VGPR cap).
//  - TH=4 (acc 16 VGPR, 10240 waves = 40/CU) for latency hiding.
//  - border lanes: clamped-base vector load + cndmask component fix
//    (1 VMEM/row for ALL lanes; no scalar-gather fallback).

#define KS 13
#define IH 1024
#define IW 1024
#define OH 256
#define OW 256
#define WOX 61              // valid outputs per wave in x (3-lane halo)
#define TH 4                // output rows per thread
#define NROWS (4 * TH + 9)  // 25 input rows per thread

__global__ __launch_bounds__(256) void degrade_kernel(
    const float* __restrict__ im,
    const float* __restrict__ kern,
    float* __restrict__ out)
{
    const int plane = blockIdx.z;          // b*4 + c
    const int b     = plane >> 2;
    const int tid   = threadIdx.x;
    const int lane  = tid & 63;
    const int w     = tid >> 6;            // wave in block
    const int ox0   = blockIdx.x * WOX;
    const int oy0   = blockIdx.y * (4 * TH) + w * TH;

    const float* __restrict__ pl = im + (size_t)plane * (IH * IW);
    const float* __restrict__ kb = kern + b * (KS * KS);   // wave-uniform

    // this lane's 16B chunk: floats fbase..fbase+3 of each input row
    const int fbase = 4 * ox0 - 8 + 4 * lane;
    const int cb    = min(max(fbase, 0), IW - 4);   // 16B-aligned clamp
    const bool interior = (fbase == cb);
    // component selectors for border lanes (0..3, runtime but loop-invariant)
    const int s0 = min(max(fbase + 0, 0), IW - 1) - cb;
    const int s1 = min(max(fbase + 1, 0), IW - 1) - cb;
    const int s2 = min(max(fbase + 2, 0), IW - 1) - cb;
    const int s3 = min(max(fbase + 3, 0), IW - 1) - cb;

    const int gy0 = 4 * oy0 - 6;

    // acc[j][p]: partial for output (oy0+j, ox0+lane-p)
    float acc[TH][4];
#pragma unroll
    for (int j = 0; j < TH; ++j)
#pragma unroll
        for (int p = 0; p < 4; ++p) acc[j][p] = 0.0f;

    auto pick = [](const float4& x, int s) -> float {
        float a = (s & 2) ? x.z : x.x;
        float bb = (s & 2) ? x.w : x.y;
        return (s & 1) ? bb : a;
    };

    // 4 phases: rows t === r (mod 4) use compile-time ky set {r,r+4,r+8,r+12}
#pragma unroll
    for (int r = 0; r < 4; ++r) {
#pragma unroll
        for (int u = 0; u < 7; ++u) {
            const int t = r + 4 * u;               // compile-time
            if (t < NROWS) {
                const int gy = min(max(gy0 + t, 0), IH - 1);
                const float* __restrict__ row = pl + (size_t)gy * IW;
                float4 x = *(const float4*)(row + cb);
                if (!interior) {                   // border lanes only
                    float4 f;
                    f.x = pick(x, s0); f.y = pick(x, s1);
                    f.z = pick(x, s2); f.w = pick(x, s3);
                    x = f;
                }
#pragma unroll
                for (int ky = r; ky < KS; ky += 4) {
                    const int j = (t - ky) >> 2;   // compile-time
                    if (j >= 0 && j < TH) {
                        const float* __restrict__ kr = kb + ky * KS;
                        // chunk float c -> tap kx=4p+c-2 of output (lane-p)
                        acc[j][0] = fmaf(x.z, kr[0],  acc[j][0]);
                        acc[j][0] = fmaf(x.w, kr[1],  acc[j][0]);
                        acc[j][1] = fmaf(x.x, kr[2],  acc[j][1]);
                        acc[j][1] = fmaf(x.y, kr[3],  acc[j][1]);
                        acc[j][1] = fmaf(x.z, kr[4],  acc[j][1]);
                        acc[j][1] = fmaf(x.w, kr[5],  acc[j][1]);
                        acc[j][2] = fmaf(x.x, kr[6],  acc[j][2]);
                        acc[j][2] = fmaf(x.y, kr[7],  acc[j][2]);
                        acc[j][2] = fmaf(x.z, kr[8],  acc[j][2]);
                        acc[j][2] = fmaf(x.w, kr[9],  acc[j][2]);
                        acc[j][3] = fmaf(x.x, kr[10], acc[j][3]);
                        acc[j][3] = fmaf(x.y, kr[11], acc[j][3]);
                        acc[j][3] = fmaf(x.z, kr[12], acc[j][3]);
                    }
                }
            }
        }
    }

    // combine partials across lanes (once) and store
    const bool valid = (lane < WOX) && (ox0 + lane < OW);
#pragma unroll
    for (int j = 0; j < TH; ++j) {
        float v = acc[j][0]
                + __shfl(acc[j][1], lane + 1, 64)
                + __shfl(acc[j][2], lane + 2, 64)
                + __shfl(acc[j][3], lane + 3, 64);
        if (valid)
            out[((size_t)plane * OH + oy0 + j) * OW + ox0 + lane] = v;
    }
}

extern "C" void kernel_launch(void* const* d_in, const int* in_sizes, int n_in,
                              void* d_out, int out_size, void* d_ws, size_t ws_size,
                              hipStream_t stream)
{
    const float* im   = (const float*)d_in[0];
    const float* kern = (const float*)d_in[1];
    float* out        = (float*)d_out;

    dim3 grid((OW + WOX - 1) / WOX,    // 5
              OH / (4 * TH),           // 16
              32);                     // 2560 blocks = 10240 waves
    degrade_kernel<<<grid, 256, 0, stream>>>(im, kern, out);
}

// Round 9
// 40.384 us; speedup vs baseline: 2.0770x; 1.2087x over previous
//
#include <hip/hip_runtime.h>

// Degrade: per-sample depthwise 13x13 cross-correlation, stride 4,
// replicate padding p=6.  im: [8,4,1024,1024] f32, kernel: [8,1,13,13] f32,
// out: [8,4,256,256] f32.
//
// R8: VALU de-bloat of R7 (measured: VALU issue ~26us of the 48.8us bench,
// ~3x the ideal 676-FMA budget).  Three fixes:
//  1. readfirstlane(tid>>6): wave id provably uniform -> oy0/gy0/row base
//     become SGPRs; per-row address cost = 1 scalar add (was per-lane
//     64-bit VALU math).
//  2. block-uniform interior/edge specialization: blocks 1..3 (60% of
//     grid; fbase proven in [236,979]) compile a body with ZERO border
//     logic (R7's runtime-selector pick was ~16 cndmask/row, likely
//     flattened into every wave).  Edge blocks keep the R7 path.
//  3. per-phase load batching: all 6-7 row loads of a ky-phase issued
//     before the phase's FMA block -> MLP ~7 (compiler was scheduling
//     loads just-before-use at VGPR 60).
// Structure otherwise R7: 1 coalesced float4 chunk/lane/row, 4 scatter
// partials, ky-phase decomposition (all tap indices compile-time),
// 3-shfl combine at the end.  TH=4, 2560 blocks.

#define KS 13
#define IH 1024
#define IW 1024
#define OH 256
#define OW 256
#define WOX 61              // valid outputs per wave in x (3-lane halo)
#define TH 4                // output rows per thread
#define NROWS (4 * TH + 9)  // 25 input rows per thread

__device__ __forceinline__ float pick_c(const float4& x, int s) {
    float a = (s & 2) ? x.z : x.x;
    float b = (s & 2) ? x.w : x.y;
    return (s & 1) ? b : a;
}

template <bool EDGE>
__device__ __forceinline__ void conv_body(
    const float* __restrict__ pl, const float* __restrict__ kb,
    int gy0, int fbase, int cb, int s0, int s1, int s2, int s3,
    bool interior, float acc[TH][4])
{
    // 4 phases: rows t === r (mod 4) share compile-time ky set
#pragma unroll
    for (int r = 0; r < 4; ++r) {
        float4 x[7];
        // ---- load batch: all rows of this phase (MLP ~7) ----
#pragma unroll
        for (int u = 0; u < 7; ++u) {
            const int t = r + 4 * u;               // compile-time
            if (t < NROWS) {
                const int gy = min(max(gy0 + t, 0), IH - 1);   // scalar
                const float* __restrict__ row = pl + (size_t)gy * IW;
                if (EDGE) {
                    float4 raw = *(const float4*)(row + cb);
                    if (!interior) {
                        float4 f;
                        f.x = pick_c(raw, s0); f.y = pick_c(raw, s1);
                        f.z = pick_c(raw, s2); f.w = pick_c(raw, s3);
                        raw = f;
                    }
                    x[u] = raw;
                } else {
                    x[u] = *(const float4*)(row + fbase);  // s-base + voff
                }
            }
        }
        // ---- FMA batch ----
#pragma unroll
        for (int u = 0; u < 7; ++u) {
            const int t = r + 4 * u;
            if (t < NROWS) {
#pragma unroll
                for (int ky = r; ky < KS; ky += 4) {
                    const int j = (t - ky) >> 2;   // compile-time
                    if (j >= 0 && j < TH) {
                        const float* __restrict__ kr = kb + ky * KS;
                        const float4& v = x[u];
                        // chunk float c -> tap kx=4p+c-2 of output (lane-p)
                        acc[j][0] = fmaf(v.z, kr[0],  acc[j][0]);
                        acc[j][0] = fmaf(v.w, kr[1],  acc[j][0]);
                        acc[j][1] = fmaf(v.x, kr[2],  acc[j][1]);
                        acc[j][1] = fmaf(v.y, kr[3],  acc[j][1]);
                        acc[j][1] = fmaf(v.z, kr[4],  acc[j][1]);
                        acc[j][1] = fmaf(v.w, kr[5],  acc[j][1]);
                        acc[j][2] = fmaf(v.x, kr[6],  acc[j][2]);
                        acc[j][2] = fmaf(v.y, kr[7],  acc[j][2]);
                        acc[j][2] = fmaf(v.z, kr[8],  acc[j][2]);
                        acc[j][2] = fmaf(v.w, kr[9],  acc[j][2]);
                        acc[j][3] = fmaf(v.x, kr[10], acc[j][3]);
                        acc[j][3] = fmaf(v.y, kr[11], acc[j][3]);
                        acc[j][3] = fmaf(v.z, kr[12], acc[j][3]);
                    }
                }
            }
        }
    }
}

__global__ __launch_bounds__(256) void degrade_kernel(
    const float* __restrict__ im,
    const float* __restrict__ kern,
    float* __restrict__ out)
{
    const int plane = blockIdx.z;          // b*4 + c
    const int b     = plane >> 2;
    const int tid   = threadIdx.x;
    const int lane  = tid & 63;
    // wave id: uniform across the wave's 64 lanes -> force SGPR
    const int w     = __builtin_amdgcn_readfirstlane(tid >> 6);
    const int ox0   = blockIdx.x * WOX;
    const int oy0   = blockIdx.y * (4 * TH) + w * TH;   // scalar

    const float* __restrict__ pl = im + (size_t)plane * (IH * IW);
    const float* __restrict__ kb = kern + b * (KS * KS);   // wave-uniform

    // this lane's 16B chunk: floats fbase..fbase+3 of each input row
    const int fbase = 4 * ox0 - 8 + 4 * lane;
    const int cb    = min(max(fbase, 0), IW - 4);
    const bool interior = (fbase == cb);
    const int s0 = min(max(fbase + 0, 0), IW - 1) - cb;
    const int s1 = min(max(fbase + 1, 0), IW - 1) - cb;
    const int s2 = min(max(fbase + 2, 0), IW - 1) - cb;
    const int s3 = min(max(fbase + 3, 0), IW - 1) - cb;

    const int gy0 = 4 * oy0 - 6;           // scalar

    float acc[TH][4];
#pragma unroll
    for (int j = 0; j < TH; ++j)
#pragma unroll
        for (int p = 0; p < 4; ++p) acc[j][p] = 0.0f;

    // blocks 1..gridDim.x-2 are provably interior (fbase in [236,979])
    if (blockIdx.x == 0 || blockIdx.x == gridDim.x - 1)
        conv_body<true >(pl, kb, gy0, fbase, cb, s0, s1, s2, s3, interior, acc);
    else
        conv_body<false>(pl, kb, gy0, fbase, cb, s0, s1, s2, s3, interior, acc);

    // combine partials across lanes (once) and store
    const bool valid = (lane < WOX) && (ox0 + lane < OW);
#pragma unroll
    for (int j = 0; j < TH; ++j) {
        float v = acc[j][0]
                + __shfl(acc[j][1], lane + 1, 64)
                + __shfl(acc[j][2], lane + 2, 64)
                + __shfl(acc[j][3], lane + 3, 64);
        if (valid)
            out[((size_t)plane * OH + oy0 + j) * OW + ox0 + lane] = v;
    }
}

extern "C" void kernel_launch(void* const* d_in, const int* in_sizes, int n_in,
                              void* d_out, int out_size, void* d_ws, size_t ws_size,
                              hipStream_t stream)
{
    const float* im   = (const float*)d_in[0];
    const float* kern = (const float*)d_in[1];
    float* out        = (float*)d_out;

    dim3 grid((OW + WOX - 1) / WOX,    // 5
              OH / (4 * TH),           // 16
              32);                     // 2560 blocks = 10240 waves
    degrade_kernel<<<grid, 256, 0, stream>>>(im, kern, out);
}